// Round 16
// baseline (301.891 us; speedup 1.0000x reference)
//
#include <hip/hip_runtime.h>
#include <hip/hip_bf16.h>

#define LRELU(x) ((x) >= 0.f ? (x) : 0.01f * (x))

typedef __attribute__((ext_vector_type(8))) short short8v;
typedef __attribute__((ext_vector_type(4))) float f32x4;

__device__ inline unsigned fenc(float x) {
    unsigned u = __float_as_uint(x);
    return (u & 0x80000000u) ? ~u : (u | 0x80000000u);
}
__device__ inline float fdec(unsigned e) {
    return __uint_as_float((e & 0x80000000u) ? (e ^ 0x80000000u) : ~e);
}

__device__ inline float wred(float v) {
#pragma unroll
    for (int o = 32; o > 0; o >>= 1) v += __shfl_xor(v, o, 64);
    return v;
}
__device__ inline float wredmax(float v) {
#pragma unroll
    for (int o = 32; o > 0; o >>= 1) v = fmaxf(v, __shfl_xor(v, o, 64));
    return v;
}

__device__ inline unsigned short f2bu(float x) {
    __hip_bfloat16 b = __float2bfloat16(x);
    return *reinterpret_cast<unsigned short*>(&b);
}
__device__ inline float bu2f(unsigned short u) {
    return __uint_as_float((unsigned)u << 16);
}

__device__ inline f32x4 mfma16(short8v a, short8v b, f32x4 c) {
    return __builtin_amdgcn_mfma_f32_16x16x32_bf16(a, b, c, 0, 0, 0);
}

// async global->LDS, 16B per lane, dest = (wave-uniform base) + lane*16
__device__ inline void gload16(const void* g, void* l) {
    __builtin_amdgcn_global_load_lds(
        (const __attribute__((address_space(1))) void*)g,
        (__attribute__((address_space(3))) void*)l, 16, 0, 0);
}

// ---- convert W matrices to transposed hi/lo bf16: Wt[n][k] = W[k][n] ----
__global__ __launch_bounds__(256) void k_convW(
    const float* __restrict__ wh, const float* __restrict__ wt,
    const float* __restrict__ hww, unsigned short* __restrict__ wtb_hi,
    unsigned short* __restrict__ wtb_lo, unsigned short* __restrict__ hwt_hi,
    unsigned short* __restrict__ hwt_lo) {
    int id = blockIdx.x * 256 + threadIdx.x;
    if (id < 256 * 256) {
        int n = id >> 8, k = id & 255;
        float v = (n < 128) ? wh[(size_t)k * 128 + n] : wt[(size_t)k * 128 + (n - 128)];
        unsigned short h = f2bu(v);
        float r = v - bu2f(h);
        wtb_hi[(size_t)n * 256 + k] = h;
        wtb_lo[(size_t)n * 256 + k] = f2bu(r);
    } else {
        int id2 = id - 256 * 256;
        if (id2 < 128 * 128) {
            int n = id2 >> 7, k = id2 & 127;
            float v = hww[(size_t)k * 128 + n];
            unsigned short h = f2bu(v);
            float r = v - bu2f(h);
            hwt_hi[(size_t)n * 128 + k] = h;
            hwt_lo[(size_t)n * 128 + k] = f2bu(r);
        }
    }
}

// ---- relation dot: er2[r] = r_emb[r]·a_r2 ----
__global__ __launch_bounds__(256) void k_rel(const float* __restrict__ remb,
                                             const float* __restrict__ ar2,
                                             float* __restrict__ er2, int NR) {
    int lane = threadIdx.x & 63;
    int r = blockIdx.x * 4 + (threadIdx.x >> 6);
    if (r >= NR) return;
    float v0 = remb[(size_t)r * 128 + lane];
    float v1 = remb[(size_t)r * 128 + 64 + lane];
    float p2 = wred(v0 * ar2[lane] + v1 * ar2[64 + lane]);
    if (lane == 0) er2[r] = p2;
}

// ---- 2-phase double-buffered LDS-staged MFMA GEMM ----
// Block 128x128; row-wave tiling (wave w: rows w*32..+31, all 128 cols,
// acc[2][8]).
// EPI 0 (proj, KD=256, A = x_e f32): DEPTH-2 A prefetch via reg ping-pong:
//   loadA(s+2) issued at step s; cvt+ds_write of step-(s+1) data lands after
//   step s's MFMA (write-late). A loads get ~2 steps in flight before use.
//   half0 -> oh0=bf16(relu(xe@wh)), hb, eh4o;
//   half1 -> oh1=bf16(relu(xe@wt)*inv) pre-normalized, pta={ta, tidx[row]}.
// EPI 1 (highway, KD=128, A bf16): gate=sigmoid(C+bias); o0=g*xeh+(1-g)*bf16(A).
template <int EPI>
__device__ __forceinline__ void mm_body(
    const float* __restrict__ Af32, const unsigned short* __restrict__ Ah,
    const unsigned short* __restrict__ Bh, const unsigned short* __restrict__ Bl,
    unsigned short* __restrict__ oh0, unsigned short* __restrict__ oh1,
    float* __restrict__ o0, const float* __restrict__ bias,
    const float* __restrict__ xeh, int M,
    const float* __restrict__ ah2, const float* __restrict__ ah3,
    const float* __restrict__ ah4, const float* __restrict__ at2,
    const float* __restrict__ at3,
    float* __restrict__ hb, float* __restrict__ eh4o,
    float2* __restrict__ pta, const int* __restrict__ tidxg) {
    constexpr int KD = (EPI == 0) ? 256 : 128;
    constexpr int NSTEP = KD / 32;
    __shared__ unsigned short As_h[2][128 * 32];
    __shared__ unsigned short Bs_h[2][128 * 32];
    __shared__ unsigned short Bs_l[2][128 * 32];

    int bx = blockIdx.x;
    int half = (EPI == 0) ? (bx & 1) : 0;
    int mblk = (EPI == 0) ? (bx >> 1) : bx;
    int row0 = mblk * 128;
    if (row0 + 128 > M) row0 = M - 128;
    int tid = threadIdx.x, w = tid >> 6, l = tid & 63;
    int lr = l & 15, hi4 = l >> 4;
    int srow = l >> 2, sslot = l & 3;

    // per-thread A staging assignment (EPI 0): 2 granules of 8 f32
    int arow0 = tid >> 2, aslot0 = tid & 3;
    int arow1 = (256 + tid) >> 2, aslot1 = tid & 3;
    int agr0 = (aslot0 ^ ((arow0 >> 1) & 3)) * 8;
    int agr1 = (aslot1 ^ ((arow1 >> 1) & 3)) * 8;
    // two register sets (depth-2 ping-pong): loadA(k) -> set k&1
    float4 rA[2][4];

    f32x4 acc[2][8];
#pragma unroll
    for (int i = 0; i < 2; i++)
#pragma unroll
        for (int j = 0; j < 8; j++) acc[i][j] = (f32x4){0.f, 0.f, 0.f, 0.f};

    auto loadA = [&](int s, int rs) {  // issue f32 loads for step s into set rs
        int k0 = s * 32;
        const float* p0 = Af32 + (size_t)(row0 + arow0) * KD + k0 + agr0;
        const float* p1 = Af32 + (size_t)(row0 + arow1) * KD + k0 + agr1;
        rA[rs][0] = *(const float4*)p0;
        rA[rs][1] = *(const float4*)(p0 + 4);
        rA[rs][2] = *(const float4*)p1;
        rA[rs][3] = *(const float4*)(p1 + 4);
    };
    auto writeA = [&](int rs, int b) {  // cvt + ds_write set rs into buf b
        short8v v0, v1;
        float x0[8] = {rA[rs][0].x, rA[rs][0].y, rA[rs][0].z, rA[rs][0].w,
                       rA[rs][1].x, rA[rs][1].y, rA[rs][1].z, rA[rs][1].w};
        float x1[8] = {rA[rs][2].x, rA[rs][2].y, rA[rs][2].z, rA[rs][2].w,
                       rA[rs][3].x, rA[rs][3].y, rA[rs][3].z, rA[rs][3].w};
#pragma unroll
        for (int j = 0; j < 8; j++) {
            v0[j] = (short)f2bu(x0[j]);
            v1[j] = (short)f2bu(x1[j]);
        }
        *(short8v*)&As_h[b][arow0 * 32 + aslot0 * 8] = v0;
        *(short8v*)&As_h[b][arow1 * 32 + aslot1 * 8] = v1;
    };
    auto stageB = [&](int s, int b) {
        int k0 = s * 32;
        constexpr int NU = (EPI == 0) ? 4 : 6;   // EPI0: 16 units; EPI1: 24
#pragma unroll
        for (int i = 0; i < NU; i++) {
            int u = w * NU + i;
            int arr = u >> 3, ld = u & 7;
            int row = ld * 16 + srow;
            int klog = (sslot ^ ((row >> 1) & 3)) * 8;
            const unsigned short* src;
            unsigned short* dst;
            if constexpr (EPI == 0) {
                src = (arr == 0 ? Bh : Bl) + (size_t)(half * 128 + row) * KD;
                dst = (arr == 0 ? Bs_h[b] : Bs_l[b]);
            } else {
                if (arr == 0)      { src = Ah + (size_t)(row0 + row) * KD; dst = As_h[b]; }
                else if (arr == 1) { src = Bh + (size_t)row * KD;          dst = Bs_h[b]; }
                else               { src = Bl + (size_t)row * KD;          dst = Bs_l[b]; }
            }
            gload16(src + k0 + klog, dst + ld * 512);
        }
    };

    if constexpr (EPI == 0) {
        loadA(0, 0);
        loadA(1, 1);
        stageB(0, 0);
        writeA(0, 0);
    } else {
        stageB(0, 0);
    }
    __syncthreads();                              // buf0 ready
    for (int s = 0; s < NSTEP; s++) {
        int b = s & 1;
        if (s + 1 < NSTEP) {
            stageB(s + 1, b ^ 1);
            if constexpr (EPI == 0)
                if (s + 2 < NSTEP) loadA(s + 2, s & 1);  // depth-2 issue
        }

        short8v am_h[2];
#pragma unroll
        for (int mr = 0; mr < 2; mr++) {
            int r = w * 32 + mr * 16 + lr;
            int ko = (hi4 ^ ((r >> 1) & 3)) * 8;
            am_h[mr] = *(const short8v*)&As_h[b][r * 32 + ko];
        }
#pragma unroll
        for (int ncc = 0; ncc < 8; ncc += 4) {   // split B loads: cap VGPR
            short8v bn_h[4], bn_l[4];
#pragma unroll
            for (int j = 0; j < 4; j++) {
                int n = (ncc + j) * 16 + lr;
                int ko = (hi4 ^ ((n >> 1) & 3)) * 8;
                bn_h[j] = *(const short8v*)&Bs_h[b][n * 32 + ko];
                bn_l[j] = *(const short8v*)&Bs_l[b][n * 32 + ko];
            }
#pragma unroll
            for (int mr = 0; mr < 2; mr++)
#pragma unroll
                for (int j = 0; j < 4; j++) {
                    acc[mr][ncc + j] = mfma16(am_h[mr], bn_h[j], acc[mr][ncc + j]);
                    acc[mr][ncc + j] = mfma16(am_h[mr], bn_l[j], acc[mr][ncc + j]);
                }
        }
        if constexpr (EPI == 0) {
            if (s + 1 < NSTEP) writeA((s + 1) & 1, b ^ 1);  // write-late
        }
        __syncthreads();  // drains next-buf loads/writes + protects swap
    }

    if constexpr (EPI == 0) {
        unsigned short* OH = half ? oh1 : oh0;
        const float* v1 = half ? at2 : ah2;
        const float* v2 = half ? at3 : ah3;
#pragma unroll
        for (int mr = 0; mr < 2; mr++)
#pragma unroll
            for (int rr = 0; rr < 4; rr++) {
                int row = row0 + w * 32 + mr * 16 + hi4 * 4 + rr;
                float d0 = 0.f, d1 = 0.f, d2 = 0.f;
#pragma unroll
                for (int nc = 0; nc < 8; nc++) {
                    float v = fmaxf(acc[mr][nc][rr], 0.f);
                    int col = nc * 16 + lr;
                    d0 = fmaf(v, v1[col], d0);
                    d1 = fmaf(v, v2[col], d1);
                    d2 = half ? fmaf(v, v, d2) : fmaf(v, ah4[col], d2);
                }
#pragma unroll
                for (int o = 1; o <= 8; o <<= 1) {   // reduce within 16-lane group
                    d0 += __shfl_xor(d0, o, 64);
                    d1 += __shfl_xor(d1, o, 64);
                    d2 += __shfl_xor(d2, o, 64);
                }
                float inv = 1.f;
                if (half) inv = 1.f / fmaxf(sqrtf(d2), 1e-12f);
#pragma unroll
                for (int nc = 0; nc < 8; nc++) {
                    float v = fmaxf(acc[mr][nc][rr], 0.f);
                    OH[(size_t)row * 128 + nc * 16 + lr] = f2bu(half ? v * inv : v);
                }
                if (lr == 0) {
                    if (half == 0) {
                        hb[row] = d0 + 0.25f * d1;
                        eh4o[row] = d2;
                    } else {
                        float tav = (d0 + 0.25f * d1) * inv;
                        pta[row] = make_float2(tav, __int_as_float(tidxg[row]));
                    }
                }
            }
    } else {
#pragma unroll
        for (int mr = 0; mr < 2; mr++)
#pragma unroll
            for (int rr = 0; rr < 4; rr++) {
                int row = row0 + w * 32 + mr * 16 + hi4 * 4 + rr;
#pragma unroll
                for (int nc = 0; nc < 8; nc++) {
                    int col = nc * 16 + lr;
                    float a = acc[mr][nc][rr] + bias[col];
                    float g = 1.f / (1.f + expf(-a));
                    size_t o = (size_t)row * 128 + col;
                    float af = bu2f(Ah[o]);
                    o0[o] = g * xeh[o] + (1.f - g) * af;
                }
            }
    }
}

__global__ __launch_bounds__(256) void k_mm_proj(
    const float* Af32, const unsigned short* Bh, const unsigned short* Bl,
    unsigned short* oh0, unsigned short* oh1, int M,
    const float* ah2, const float* ah3, const float* ah4,
    const float* at2, const float* at3,
    float* hb, float* eh4o, float2* pta, const int* tidxg) {
    mm_body<0>(Af32, nullptr, Bh, Bl, oh0, oh1, nullptr, nullptr, nullptr, M,
               ah2, ah3, ah4, at2, at3, hb, eh4o, pta, tidxg);
}

__global__ __launch_bounds__(256) void k_mm_hw(
    const unsigned short* Ah, const unsigned short* Bh, const unsigned short* Bl,
    float* o0, const float* bias, const float* xeh, int M) {
    mm_body<1>(nullptr, Ah, Bh, Bl, nullptr, nullptr, o0, bias, xeh, M,
               nullptr, nullptr, nullptr, nullptr, nullptr,
               nullptr, nullptr, nullptr, nullptr);
}

// ---- counting sort by class_index ----
__global__ __launch_bounds__(256) void k_hist(const int* __restrict__ cidx,
                                              int* __restrict__ cnt, int E) {
    int i = blockIdx.x * 256 + threadIdx.x;
    if (i >= E) return;
    atomicAdd(&cnt[cidx[i]], 1);
}

__global__ __launch_bounds__(1024) void k_scan(const int* __restrict__ cnt,
                                               int* __restrict__ off,
                                               int* __restrict__ cur, int NC) {
    __shared__ int wt[16];
    __shared__ int sbase;
    int tid = threadIdx.x, w = tid >> 6, lane = tid & 63;
    if (tid == 0) sbase = 0;
    __syncthreads();
    for (int c0 = 0; c0 < NC; c0 += 1024) {
        int c = c0 + tid;
        int v = (c < NC) ? cnt[c] : 0;
        int x = v;
#pragma unroll
        for (int o = 1; o < 64; o <<= 1) {
            int t = __shfl_up(x, o, 64);
            if (lane >= o) x += t;
        }
        if (lane == 63) wt[w] = x;
        __syncthreads();
        int pre = 0, tot = 0;
#pragma unroll
        for (int i = 0; i < 16; i++) {
            int t = wt[i];
            tot += t;
            if (i < w) pre += t;
        }
        int excl = sbase + pre + x - v;
        if (c < NC) { off[c] = excl; cur[c] = excl; }
        __syncthreads();
        if (tid == 0) sbase += tot;
        __syncthreads();
    }
}

// ---- fused level-2 logit + scatter (packed 8B gather + packed 8B write) ----
// z2 = lrelu(pta[te].ta + hb[h] + 0.5*er2[rel]); g = pta[te].g
__global__ __launch_bounds__(256) void k_edgescatter(
    const int* __restrict__ cidx, int* __restrict__ cur,
    const int* __restrict__ hidx, const int* __restrict__ tidx,
    const int* __restrict__ rel, const float2* __restrict__ pta,
    const float* __restrict__ hb, const float* __restrict__ er2,
    float2* __restrict__ e2gs, int E) {
    int i = blockIdx.x * 256 + threadIdx.x;
    if (i >= E) return;
    int pos = atomicAdd(&cur[cidx[i]], 1);
    float2 p = pta[tidx[i]];
    float z2 = p.x + hb[hidx[i]] + 0.5f * er2[rel[i]];
    e2gs[pos] = make_float2(LRELU(z2), p.y);
}

// ---- fused level-2 softmax + spmm + class-dot, one wave/class ----
// rows gathered from PRE-NORMALIZED bf16 xrtn; e2gs = {logit, g} pairs.
__global__ __launch_bounds__(256) void k_spmm2(
    const int* __restrict__ off, const int* __restrict__ cnt,
    const float2* __restrict__ e2gs, const unsigned* __restrict__ xrtn_b,
    float* __restrict__ xclass, const float* __restrict__ ac,
    const float* __restrict__ eh4, const int* __restrict__ hclass,
    float* __restrict__ zc, unsigned* __restrict__ m3, int NC) {
    int lane = threadIdx.x & 63;
    int c = blockIdx.x * 4 + (threadIdx.x >> 6);
    if (c >= NC) return;
    int n = cnt[c];
    float a0 = 0.f, a1 = 0.f;
    if (n > 0) {
        int base = off[c];
        float m = -3.4e38f, s = 0.f;
        for (int j = lane; j < n; j += 64) {
            float z = e2gs[base + j].x;
            if (z > m) { s = s * __expf(m - z) + 1.f; m = z; }
            else s += __expf(z - m);
        }
        float M = wredmax(m);
        s = wred(s * __expf(m - M));
        float inv = 1.f / (s + 1e-16f);
        for (int j0 = 0; j0 < n; j0 += 64) {
            int lim = n - j0;
            if (lim > 64) lim = 64;
            float wv = 0.f;
            int g = 0;
            if (lane < lim) {
                float2 pg = e2gs[base + j0 + lane];
                wv = __expf(pg.x - M) * inv;
                g = __float_as_int(pg.y);
            }
            int jj = 0;
            for (; jj + 8 <= lim; jj += 8) {  // 8 rows in flight, 256B each
                float w0 = __shfl(wv, jj + 0), w1 = __shfl(wv, jj + 1);
                float w2 = __shfl(wv, jj + 2), w3 = __shfl(wv, jj + 3);
                float w4 = __shfl(wv, jj + 4), w5 = __shfl(wv, jj + 5);
                float w6 = __shfl(wv, jj + 6), w7 = __shfl(wv, jj + 7);
                unsigned u0 = xrtn_b[(size_t)__shfl(g, jj + 0) * 64 + lane];
                unsigned u1 = xrtn_b[(size_t)__shfl(g, jj + 1) * 64 + lane];
                unsigned u2 = xrtn_b[(size_t)__shfl(g, jj + 2) * 64 + lane];
                unsigned u3 = xrtn_b[(size_t)__shfl(g, jj + 3) * 64 + lane];
                unsigned u4 = xrtn_b[(size_t)__shfl(g, jj + 4) * 64 + lane];
                unsigned u5 = xrtn_b[(size_t)__shfl(g, jj + 5) * 64 + lane];
                unsigned u6 = xrtn_b[(size_t)__shfl(g, jj + 6) * 64 + lane];
                unsigned u7 = xrtn_b[(size_t)__shfl(g, jj + 7) * 64 + lane];
                a0 = fmaf(w0, bu2f((unsigned short)(u0 & 0xffff)), a0);
                a1 = fmaf(w0, bu2f((unsigned short)(u0 >> 16)), a1);
                a0 = fmaf(w1, bu2f((unsigned short)(u1 & 0xffff)), a0);
                a1 = fmaf(w1, bu2f((unsigned short)(u1 >> 16)), a1);
                a0 = fmaf(w2, bu2f((unsigned short)(u2 & 0xffff)), a0);
                a1 = fmaf(w2, bu2f((unsigned short)(u2 >> 16)), a1);
                a0 = fmaf(w3, bu2f((unsigned short)(u3 & 0xffff)), a0);
                a1 = fmaf(w3, bu2f((unsigned short)(u3 >> 16)), a1);
                a0 = fmaf(w4, bu2f((unsigned short)(u4 & 0xffff)), a0);
                a1 = fmaf(w4, bu2f((unsigned short)(u4 >> 16)), a1);
                a0 = fmaf(w5, bu2f((unsigned short)(u5 & 0xffff)), a0);
                a1 = fmaf(w5, bu2f((unsigned short)(u5 >> 16)), a1);
                a0 = fmaf(w6, bu2f((unsigned short)(u6 & 0xffff)), a0);
                a1 = fmaf(w6, bu2f((unsigned short)(u6 >> 16)), a1);
                a0 = fmaf(w7, bu2f((unsigned short)(u7 & 0xffff)), a0);
                a1 = fmaf(w7, bu2f((unsigned short)(u7 >> 16)), a1);
            }
            for (; jj < lim; jj++) {
                float wj = __shfl(wv, jj);
                unsigned u = xrtn_b[(size_t)__shfl(g, jj) * 64 + lane];
                a0 = fmaf(wj, bu2f((unsigned short)(u & 0xffff)), a0);
                a1 = fmaf(wj, bu2f((unsigned short)(u >> 16)), a1);
            }
        }
    }
    *(float2*)&xclass[(size_t)c * 128 + 2 * lane] = make_float2(a0, a1);
    // fused class-level dot: e_c = xclass[c]·ac + eh4[hclass[c]]
    float p = wred(a0 * ac[2 * lane] + a1 * ac[2 * lane + 1]);
    if (lane == 0) {
        int hc = hclass[c];
        float z = LRELU(p + eh4[hc]);
        zc[c] = z;
        atomicMax(&m3[hc], fenc(z));
    }
}

// ---- level 3: class -> head entity ----
__global__ __launch_bounds__(256) void k_class2(const int* __restrict__ hclass,
                                                float* __restrict__ zc,
                                                const unsigned* __restrict__ m3,
                                                float* __restrict__ s3, int NC) {
    int c = blockIdx.x * 256 + threadIdx.x;
    if (c >= NC) return;
    int hc = hclass[c];
    float ex = expf(zc[c] - fdec(m3[hc]));
    zc[c] = ex;
    atomicAdd(&s3[hc], ex);
}

__global__ __launch_bounds__(256) void k_class3(
    const int* __restrict__ hclass, const float* __restrict__ zc,
    const float* __restrict__ s3, const float* __restrict__ xclass,
    float* __restrict__ xeh, int NC) {
    int lane = threadIdx.x & 63;
    int c = blockIdx.x * 4 + (threadIdx.x >> 6);
    if (c >= NC) return;
    int hc = hclass[c];
    float gama = zc[c] / (s3[hc] + 1e-16f);
    float v0 = xclass[(size_t)c * 128 + lane], v1 = xclass[(size_t)c * 128 + 64 + lane];
    atomicAdd(&xeh[(size_t)hc * 128 + lane], gama * v0);
    atomicAdd(&xeh[(size_t)hc * 128 + 64 + lane], gama * v1);
}

extern "C" void kernel_launch(void* const* d_in, const int* in_sizes, int n_in,
                              void* d_out, int out_size, void* d_ws, size_t ws_size,
                              hipStream_t stream) {
    (void)n_in; (void)out_size; (void)ws_size;
    const float* xe   = (const float*)d_in[0];
    const int*   eidx = (const int*)d_in[1];
    const int*   rel  = (const int*)d_in[2];
    const float* remb = (const float*)d_in[4];
    const int*   cidx = (const int*)d_in[5];
    const int*   hcls = (const int*)d_in[6];
    const float* ah2  = (const float*)d_in[8];
    const float* ah3  = (const float*)d_in[9];
    const float* ah4  = (const float*)d_in[10];
    const float* at2  = (const float*)d_in[12];
    const float* at3  = (const float*)d_in[13];
    const float* ar2  = (const float*)d_in[15];
    const float* ac   = (const float*)d_in[16];
    const float* wh   = (const float*)d_in[17];
    const float* wt   = (const float*)d_in[18];
    const float* hww  = (const float*)d_in[19];
    const float* hwb  = (const float*)d_in[20];
    float* out = (float*)d_out;

    const int NE = in_sizes[0] / 256;
    const int E  = in_sizes[2];
    const int NR = in_sizes[4] / 128;
    const int NC = in_sizes[6];
    const int* hidx = eidx;
    const int* tidx = eidx + E;

    char* base = (char*)d_ws;
    size_t off0 = 0;
    auto alloc = [&](size_t bytes) -> char* {
        char* r = base + off0;
        off0 = (off0 + bytes + 255) & ~(size_t)255;
        return r;
    };
    float* hb   = (float*)alloc((size_t)NE * 4);
    float* eh4b = (float*)alloc((size_t)NE * 4);
    float2* pta = (float2*)alloc((size_t)NE * 8);
    float* er2b = (float*)alloc((size_t)NR * 4);
    float2* e2gs = (float2*)alloc((size_t)E * 8);
    float* zc   = (float*)alloc((size_t)NC * 4);
    unsigned short* wtb_hi = (unsigned short*)alloc((size_t)256 * 256 * 2);
    unsigned short* wtb_lo = (unsigned short*)alloc((size_t)256 * 256 * 2);
    unsigned short* hwt_hi = (unsigned short*)alloc((size_t)128 * 128 * 2);
    unsigned short* hwt_lo = (unsigned short*)alloc((size_t)128 * 128 * 2);
    unsigned short* xrh_hi = (unsigned short*)alloc((size_t)NE * 128 * 2);
    unsigned short* xrtn   = (unsigned short*)alloc((size_t)NE * 128 * 2);
    int* offb = (int*)alloc((size_t)NC * 4);
    int* curb = (int*)alloc((size_t)NC * 4);
    float* xclass = (float*)alloc((size_t)NC * 128 * 4);
    size_t zoff = off0;  // everything below is zero-initialized per launch
    unsigned* m3 = (unsigned*)alloc((size_t)NE * 4);
    float* s3    = (float*)alloc((size_t)NE * 4);
    int* cntb    = (int*)alloc((size_t)NC * 4);
    float* xeh   = (float*)alloc((size_t)NE * 128 * 4);
    size_t zbytes = off0 - zoff;

    hipMemsetAsync(base + zoff, 0, zbytes, stream);

    k_convW<<<(256 * 256 + 128 * 128 + 255) / 256, 256, 0, stream>>>(
        wh, wt, hww, wtb_hi, wtb_lo, hwt_hi, hwt_lo);
    k_rel<<<(NR + 3) / 4, 256, 0, stream>>>(remb, ar2, er2b, NR);

    // projection GEMM: depth-2 reg-staged A (f32 direct), bf16 mirrors
    // (xrt pre-normalized) + fused dots + packed pta records
    k_mm_proj<<<((NE + 127) / 128) * 2, 256, 0, stream>>>(
        xe, wtb_hi, wtb_lo, xrh_hi, xrtn, NE,
        ah2, ah3, ah4, at2, at3, hb, eh4b, pta, tidx);

    // class-CSR histogram/scan
    k_hist<<<(E + 255) / 256, 256, 0, stream>>>(cidx, cntb, E);
    k_scan<<<1, 1024, 0, stream>>>(cntb, offb, curb, NC);

    // fused level-2 logit + scatter (level-1 softmax cancels vs F.normalize)
    k_edgescatter<<<(E + 255) / 256, 256, 0, stream>>>(
        cidx, curb, hidx, tidx, rel, pta, hb, er2b, e2gs, E);

    k_spmm2<<<(NC + 3) / 4, 256, 0, stream>>>(offb, cntb, e2gs,
                                              (const unsigned*)xrtn, xclass,
                                              ac, eh4b, hcls, zc, m3, NC);
    k_class2<<<(NC + 255) / 256, 256, 0, stream>>>(hcls, zc, m3, s3, NC);
    k_class3<<<(NC + 3) / 4, 256, 0, stream>>>(hcls, zc, s3, xclass, xeh, NC);

    k_mm_hw<<<(NE + 127) / 128, 256, 0, stream>>>(
        xrh_hi, hwt_hi, hwt_lo, out, hwb, xeh, NE);
}

// Round 17
// 282.305 us; speedup vs baseline: 1.0694x; 1.0694x over previous
//
#include <hip/hip_runtime.h>
#include <hip/hip_bf16.h>

#define LRELU(x) ((x) >= 0.f ? (x) : 0.01f * (x))

typedef __attribute__((ext_vector_type(8))) short short8v;
typedef __attribute__((ext_vector_type(4))) float f32x4;

__device__ inline unsigned fenc(float x) {
    unsigned u = __float_as_uint(x);
    return (u & 0x80000000u) ? ~u : (u | 0x80000000u);
}
__device__ inline float fdec(unsigned e) {
    return __uint_as_float((e & 0x80000000u) ? (e ^ 0x80000000u) : ~e);
}

__device__ inline float wred(float v) {
#pragma unroll
    for (int o = 32; o > 0; o >>= 1) v += __shfl_xor(v, o, 64);
    return v;
}
__device__ inline float wredmax(float v) {
#pragma unroll
    for (int o = 32; o > 0; o >>= 1) v = fmaxf(v, __shfl_xor(v, o, 64));
    return v;
}

__device__ inline unsigned short f2bu(float x) {
    __hip_bfloat16 b = __float2bfloat16(x);
    return *reinterpret_cast<unsigned short*>(&b);
}
__device__ inline float bu2f(unsigned short u) {
    return __uint_as_float((unsigned)u << 16);
}

__device__ inline f32x4 mfma16(short8v a, short8v b, f32x4 c) {
    return __builtin_amdgcn_mfma_f32_16x16x32_bf16(a, b, c, 0, 0, 0);
}

// async global->LDS, 16B per lane, dest = (wave-uniform base) + lane*16
__device__ inline void gload16(const void* g, void* l) {
    __builtin_amdgcn_global_load_lds(
        (const __attribute__((address_space(1))) void*)g,
        (__attribute__((address_space(3))) void*)l, 16, 0, 0);
}

// ---- convert W matrices to transposed bf16: Wt[n][k] = bf16(W[k][n]) ----
__global__ __launch_bounds__(256) void k_convW(
    const float* __restrict__ wh, const float* __restrict__ wt,
    const float* __restrict__ hww, unsigned short* __restrict__ wtb_hi,
    unsigned short* __restrict__ hwt_hi) {
    int id = blockIdx.x * 256 + threadIdx.x;
    if (id < 256 * 256) {
        int n = id >> 8, k = id & 255;
        float v = (n < 128) ? wh[(size_t)k * 128 + n] : wt[(size_t)k * 128 + (n - 128)];
        wtb_hi[(size_t)n * 256 + k] = f2bu(v);
    } else {
        int id2 = id - 256 * 256;
        if (id2 < 128 * 128) {
            int n = id2 >> 7, k = id2 & 127;
            hwt_hi[(size_t)n * 128 + k] = f2bu(hww[(size_t)k * 128 + n]);
        }
    }
}

// ---- relation dot: er2[r] = r_emb[r]·a_r2 ----
__global__ __launch_bounds__(256) void k_rel(const float* __restrict__ remb,
                                             const float* __restrict__ ar2,
                                             float* __restrict__ er2, int NR) {
    int lane = threadIdx.x & 63;
    int r = blockIdx.x * 4 + (threadIdx.x >> 6);
    if (r >= NR) return;
    float v0 = remb[(size_t)r * 128 + lane];
    float v1 = remb[(size_t)r * 128 + 64 + lane];
    float p2 = wred(v0 * ar2[lane] + v1 * ar2[64 + lane]);
    if (lane == 0) er2[r] = p2;
}

// ---- 2-phase double-buffered LDS-staged MFMA GEMM, bf16 A and B ----
// Block 128x128; row-wave tiling (wave w: rows w*32..+31, all 128 cols,
// acc[2][8]); 16 MFMA/step. Per step: issue next A f32 loads (EPI0) + B
// gloads -> MFMA(cur) -> cvt+ds_write next A (write-late) -> barrier.
// EPI 0 (proj, KD=256, A = x_e f32 converted in-kernel):
//   half0 -> oh0=bf16(relu(xe@wh)), hb, eh4o;
//   half1 -> oh1=bf16(relu(xe@wt)*inv) pre-normalized, pta={ta, tidx[row]}.
// EPI 1 (highway, KD=128, A bf16): gate=sigmoid(C+bias); o0=g*xeh+(1-g)*bf16(A).
template <int EPI>
__device__ __forceinline__ void mm_body(
    const float* __restrict__ Af32, const unsigned short* __restrict__ Ah,
    const unsigned short* __restrict__ Bh,
    unsigned short* __restrict__ oh0, unsigned short* __restrict__ oh1,
    float* __restrict__ o0, const float* __restrict__ bias,
    const float* __restrict__ xeh, int M,
    const float* __restrict__ ah2, const float* __restrict__ ah3,
    const float* __restrict__ ah4, const float* __restrict__ at2,
    const float* __restrict__ at3,
    float* __restrict__ hb, float* __restrict__ eh4o,
    float2* __restrict__ pta, const int* __restrict__ tidxg) {
    constexpr int KD = (EPI == 0) ? 256 : 128;
    constexpr int NSTEP = KD / 32;
    __shared__ unsigned short As_h[2][128 * 32];
    __shared__ unsigned short Bs_h[2][128 * 32];

    int bx = blockIdx.x;
    int half = (EPI == 0) ? (bx & 1) : 0;
    int mblk = (EPI == 0) ? (bx >> 1) : bx;
    int row0 = mblk * 128;
    if (row0 + 128 > M) row0 = M - 128;
    int tid = threadIdx.x, w = tid >> 6, l = tid & 63;
    int lr = l & 15, hi4 = l >> 4;
    int srow = l >> 2, sslot = l & 3;

    // per-thread A staging assignment (EPI 0): 2 granules of 8 f32
    int arow0 = tid >> 2, aslot0 = tid & 3;
    int arow1 = (256 + tid) >> 2, aslot1 = tid & 3;
    int agr0 = (aslot0 ^ ((arow0 >> 1) & 3)) * 8;
    int agr1 = (aslot1 ^ ((arow1 >> 1) & 3)) * 8;
    float4 rA[4];

    f32x4 acc[2][8];
#pragma unroll
    for (int i = 0; i < 2; i++)
#pragma unroll
        for (int j = 0; j < 8; j++) acc[i][j] = (f32x4){0.f, 0.f, 0.f, 0.f};

    auto loadA = [&](int s) {  // EPI 0: issue f32 loads for step s
        int k0 = s * 32;
        const float* p0 = Af32 + (size_t)(row0 + arow0) * KD + k0 + agr0;
        const float* p1 = Af32 + (size_t)(row0 + arow1) * KD + k0 + agr1;
        rA[0] = *(const float4*)p0;
        rA[1] = *(const float4*)(p0 + 4);
        rA[2] = *(const float4*)p1;
        rA[3] = *(const float4*)(p1 + 4);
    };
    auto writeA = [&](int b) {  // EPI 0: cvt + ds_write into buf b
        short8v v0, v1;
        float x0[8] = {rA[0].x, rA[0].y, rA[0].z, rA[0].w,
                       rA[1].x, rA[1].y, rA[1].z, rA[1].w};
        float x1[8] = {rA[2].x, rA[2].y, rA[2].z, rA[2].w,
                       rA[3].x, rA[3].y, rA[3].z, rA[3].w};
#pragma unroll
        for (int j = 0; j < 8; j++) {
            v0[j] = (short)f2bu(x0[j]);
            v1[j] = (short)f2bu(x1[j]);
        }
        *(short8v*)&As_h[b][arow0 * 32 + aslot0 * 8] = v0;
        *(short8v*)&As_h[b][arow1 * 32 + aslot1 * 8] = v1;
    };
    auto stageB = [&](int s, int b) {
        int k0 = s * 32;
        constexpr int NU = (EPI == 0) ? 2 : 4;   // EPI0: 8 units; EPI1: 16
#pragma unroll
        for (int i = 0; i < NU; i++) {
            int u = w * NU + i;
            int arr = u >> 3, ld = u & 7;
            int row = ld * 16 + srow;
            int klog = (sslot ^ ((row >> 1) & 3)) * 8;
            const unsigned short* src;
            unsigned short* dst;
            if constexpr (EPI == 0) {
                src = Bh + (size_t)(half * 128 + row) * KD;
                dst = Bs_h[b];
            } else {
                if (arr == 0) { src = Ah + (size_t)(row0 + row) * KD; dst = As_h[b]; }
                else          { src = Bh + (size_t)row * KD;          dst = Bs_h[b]; }
            }
            gload16(src + k0 + klog, dst + ld * 512);
        }
    };

    if constexpr (EPI == 0) {
        loadA(0);
        stageB(0, 0);
        writeA(0);
    } else {
        stageB(0, 0);
    }
    __syncthreads();                              // buf0 ready
    for (int s = 0; s < NSTEP; s++) {
        int b = s & 1;
        if (s + 1 < NSTEP) {
            if constexpr (EPI == 0) loadA(s + 1);  // issue early
            stageB(s + 1, b ^ 1);
        }

        short8v am_h[2];
#pragma unroll
        for (int mr = 0; mr < 2; mr++) {
            int r = w * 32 + mr * 16 + lr;
            int ko = (hi4 ^ ((r >> 1) & 3)) * 8;
            am_h[mr] = *(const short8v*)&As_h[b][r * 32 + ko];
        }
#pragma unroll
        for (int ncc = 0; ncc < 8; ncc += 4) {   // split B loads: cap VGPR
            short8v bn_h[4];
#pragma unroll
            for (int j = 0; j < 4; j++) {
                int n = (ncc + j) * 16 + lr;
                int ko = (hi4 ^ ((n >> 1) & 3)) * 8;
                bn_h[j] = *(const short8v*)&Bs_h[b][n * 32 + ko];
            }
#pragma unroll
            for (int mr = 0; mr < 2; mr++)
#pragma unroll
                for (int j = 0; j < 4; j++)
                    acc[mr][ncc + j] = mfma16(am_h[mr], bn_h[j], acc[mr][ncc + j]);
        }
        if constexpr (EPI == 0) {
            if (s + 1 < NSTEP) writeA(b ^ 1);    // write late, under MFMA shadow
        }
        __syncthreads();  // drains next-buf loads/writes + protects swap
    }

    if constexpr (EPI == 0) {
        unsigned short* OH = half ? oh1 : oh0;
        const float* v1 = half ? at2 : ah2;
        const float* v2 = half ? at3 : ah3;
#pragma unroll
        for (int mr = 0; mr < 2; mr++)
#pragma unroll
            for (int rr = 0; rr < 4; rr++) {
                int row = row0 + w * 32 + mr * 16 + hi4 * 4 + rr;
                float d0 = 0.f, d1 = 0.f, d2 = 0.f;
#pragma unroll
                for (int nc = 0; nc < 8; nc++) {
                    float v = fmaxf(acc[mr][nc][rr], 0.f);
                    int col = nc * 16 + lr;
                    d0 = fmaf(v, v1[col], d0);
                    d1 = fmaf(v, v2[col], d1);
                    d2 = half ? fmaf(v, v, d2) : fmaf(v, ah4[col], d2);
                }
#pragma unroll
                for (int o = 1; o <= 8; o <<= 1) {   // reduce within 16-lane group
                    d0 += __shfl_xor(d0, o, 64);
                    d1 += __shfl_xor(d1, o, 64);
                    d2 += __shfl_xor(d2, o, 64);
                }
                float inv = 1.f;
                if (half) inv = 1.f / fmaxf(sqrtf(d2), 1e-12f);
#pragma unroll
                for (int nc = 0; nc < 8; nc++) {
                    float v = fmaxf(acc[mr][nc][rr], 0.f);
                    OH[(size_t)row * 128 + nc * 16 + lr] = f2bu(half ? v * inv : v);
                }
                if (lr == 0) {
                    if (half == 0) {
                        hb[row] = d0 + 0.25f * d1;
                        eh4o[row] = d2;
                    } else {
                        float tav = (d0 + 0.25f * d1) * inv;
                        pta[row] = make_float2(tav, __int_as_float(tidxg[row]));
                    }
                }
            }
    } else {
#pragma unroll
        for (int mr = 0; mr < 2; mr++)
#pragma unroll
            for (int rr = 0; rr < 4; rr++) {
                int row = row0 + w * 32 + mr * 16 + hi4 * 4 + rr;
#pragma unroll
                for (int nc = 0; nc < 8; nc++) {
                    int col = nc * 16 + lr;
                    float a = acc[mr][nc][rr] + bias[col];
                    float g = 1.f / (1.f + expf(-a));
                    size_t o = (size_t)row * 128 + col;
                    float af = bu2f(Ah[o]);
                    o0[o] = g * xeh[o] + (1.f - g) * af;
                }
            }
    }
}

__global__ __launch_bounds__(256) void k_mm_proj(
    const float* Af32, const unsigned short* Bh,
    unsigned short* oh0, unsigned short* oh1, int M,
    const float* ah2, const float* ah3, const float* ah4,
    const float* at2, const float* at3,
    float* hb, float* eh4o, float2* pta, const int* tidxg) {
    mm_body<0>(Af32, nullptr, Bh, oh0, oh1, nullptr, nullptr, nullptr, M,
               ah2, ah3, ah4, at2, at3, hb, eh4o, pta, tidxg);
}

__global__ __launch_bounds__(256) void k_mm_hw(
    const unsigned short* Ah, const unsigned short* Bh,
    float* o0, const float* bias, const float* xeh, int M) {
    mm_body<1>(nullptr, Ah, Bh, nullptr, nullptr, o0, bias, xeh, M,
               nullptr, nullptr, nullptr, nullptr, nullptr,
               nullptr, nullptr, nullptr, nullptr);
}

// ---- counting sort by class_index ----
__global__ __launch_bounds__(256) void k_hist(const int* __restrict__ cidx,
                                              int* __restrict__ cnt, int E) {
    int i = blockIdx.x * 256 + threadIdx.x;
    if (i >= E) return;
    atomicAdd(&cnt[cidx[i]], 1);
}

__global__ __launch_bounds__(1024) void k_scan(const int* __restrict__ cnt,
                                               int* __restrict__ off,
                                               int* __restrict__ cur, int NC) {
    __shared__ int wt[16];
    __shared__ int sbase;
    int tid = threadIdx.x, w = tid >> 6, lane = tid & 63;
    if (tid == 0) sbase = 0;
    __syncthreads();
    for (int c0 = 0; c0 < NC; c0 += 1024) {
        int c = c0 + tid;
        int v = (c < NC) ? cnt[c] : 0;
        int x = v;
#pragma unroll
        for (int o = 1; o < 64; o <<= 1) {
            int t = __shfl_up(x, o, 64);
            if (lane >= o) x += t;
        }
        if (lane == 63) wt[w] = x;
        __syncthreads();
        int pre = 0, tot = 0;
#pragma unroll
        for (int i = 0; i < 16; i++) {
            int t = wt[i];
            tot += t;
            if (i < w) pre += t;
        }
        int excl = sbase + pre + x - v;
        if (c < NC) { off[c] = excl; cur[c] = excl; }
        __syncthreads();
        if (tid == 0) sbase += tot;
        __syncthreads();
    }
}

// ---- fused level-2 logit + scatter (packed 8B gather + packed 8B write) ----
// z2 = lrelu(pta[te].ta + hb[h] + 0.5*er2[rel]); g = pta[te].g
__global__ __launch_bounds__(256) void k_edgescatter(
    const int* __restrict__ cidx, int* __restrict__ cur,
    const int* __restrict__ hidx, const int* __restrict__ tidx,
    const int* __restrict__ rel, const float2* __restrict__ pta,
    const float* __restrict__ hb, const float* __restrict__ er2,
    float2* __restrict__ e2gs, int E) {
    int i = blockIdx.x * 256 + threadIdx.x;
    if (i >= E) return;
    int pos = atomicAdd(&cur[cidx[i]], 1);
    float2 p = pta[tidx[i]];
    float z2 = p.x + hb[hidx[i]] + 0.5f * er2[rel[i]];
    e2gs[pos] = make_float2(LRELU(z2), p.y);
}

// ---- fused level-2 softmax + spmm + class-dot, one wave/class ----
// rows gathered from PRE-NORMALIZED bf16 xrtn; e2gs = {logit, g} pairs.
__global__ __launch_bounds__(256) void k_spmm2(
    const int* __restrict__ off, const int* __restrict__ cnt,
    const float2* __restrict__ e2gs, const unsigned* __restrict__ xrtn_b,
    float* __restrict__ xclass, const float* __restrict__ ac,
    const float* __restrict__ eh4, const int* __restrict__ hclass,
    float* __restrict__ zc, unsigned* __restrict__ m3, int NC) {
    int lane = threadIdx.x & 63;
    int c = blockIdx.x * 4 + (threadIdx.x >> 6);
    if (c >= NC) return;
    int n = cnt[c];
    float a0 = 0.f, a1 = 0.f;
    if (n > 0) {
        int base = off[c];
        float m = -3.4e38f, s = 0.f;
        for (int j = lane; j < n; j += 64) {
            float z = e2gs[base + j].x;
            if (z > m) { s = s * __expf(m - z) + 1.f; m = z; }
            else s += __expf(z - m);
        }
        float M = wredmax(m);
        s = wred(s * __expf(m - M));
        float inv = 1.f / (s + 1e-16f);
        for (int j0 = 0; j0 < n; j0 += 64) {
            int lim = n - j0;
            if (lim > 64) lim = 64;
            float wv = 0.f;
            int g = 0;
            if (lane < lim) {
                float2 pg = e2gs[base + j0 + lane];
                wv = __expf(pg.x - M) * inv;
                g = __float_as_int(pg.y);
            }
            int jj = 0;
            for (; jj + 8 <= lim; jj += 8) {  // 8 rows in flight, 256B each
                float w0 = __shfl(wv, jj + 0), w1 = __shfl(wv, jj + 1);
                float w2 = __shfl(wv, jj + 2), w3 = __shfl(wv, jj + 3);
                float w4 = __shfl(wv, jj + 4), w5 = __shfl(wv, jj + 5);
                float w6 = __shfl(wv, jj + 6), w7 = __shfl(wv, jj + 7);
                unsigned u0 = xrtn_b[(size_t)__shfl(g, jj + 0) * 64 + lane];
                unsigned u1 = xrtn_b[(size_t)__shfl(g, jj + 1) * 64 + lane];
                unsigned u2 = xrtn_b[(size_t)__shfl(g, jj + 2) * 64 + lane];
                unsigned u3 = xrtn_b[(size_t)__shfl(g, jj + 3) * 64 + lane];
                unsigned u4 = xrtn_b[(size_t)__shfl(g, jj + 4) * 64 + lane];
                unsigned u5 = xrtn_b[(size_t)__shfl(g, jj + 5) * 64 + lane];
                unsigned u6 = xrtn_b[(size_t)__shfl(g, jj + 6) * 64 + lane];
                unsigned u7 = xrtn_b[(size_t)__shfl(g, jj + 7) * 64 + lane];
                a0 = fmaf(w0, bu2f((unsigned short)(u0 & 0xffff)), a0);
                a1 = fmaf(w0, bu2f((unsigned short)(u0 >> 16)), a1);
                a0 = fmaf(w1, bu2f((unsigned short)(u1 & 0xffff)), a0);
                a1 = fmaf(w1, bu2f((unsigned short)(u1 >> 16)), a1);
                a0 = fmaf(w2, bu2f((unsigned short)(u2 & 0xffff)), a0);
                a1 = fmaf(w2, bu2f((unsigned short)(u2 >> 16)), a1);
                a0 = fmaf(w3, bu2f((unsigned short)(u3 & 0xffff)), a0);
                a1 = fmaf(w3, bu2f((unsigned short)(u3 >> 16)), a1);
                a0 = fmaf(w4, bu2f((unsigned short)(u4 & 0xffff)), a0);
                a1 = fmaf(w4, bu2f((unsigned short)(u4 >> 16)), a1);
                a0 = fmaf(w5, bu2f((unsigned short)(u5 & 0xffff)), a0);
                a1 = fmaf(w5, bu2f((unsigned short)(u5 >> 16)), a1);
                a0 = fmaf(w6, bu2f((unsigned short)(u6 & 0xffff)), a0);
                a1 = fmaf(w6, bu2f((unsigned short)(u6 >> 16)), a1);
                a0 = fmaf(w7, bu2f((unsigned short)(u7 & 0xffff)), a0);
                a1 = fmaf(w7, bu2f((unsigned short)(u7 >> 16)), a1);
            }
            for (; jj < lim; jj++) {
                float wj = __shfl(wv, jj);
                unsigned u = xrtn_b[(size_t)__shfl(g, jj) * 64 + lane];
                a0 = fmaf(wj, bu2f((unsigned short)(u & 0xffff)), a0);
                a1 = fmaf(wj, bu2f((unsigned short)(u >> 16)), a1);
            }
        }
    }
    *(float2*)&xclass[(size_t)c * 128 + 2 * lane] = make_float2(a0, a1);
    // fused class-level dot: e_c = xclass[c]·ac + eh4[hclass[c]]
    float p = wred(a0 * ac[2 * lane] + a1 * ac[2 * lane + 1]);
    if (lane == 0) {
        int hc = hclass[c];
        float z = LRELU(p + eh4[hc]);
        zc[c] = z;
        atomicMax(&m3[hc], fenc(z));
    }
}

// ---- level 3: class -> head entity ----
__global__ __launch_bounds__(256) void k_class2(const int* __restrict__ hclass,
                                                float* __restrict__ zc,
                                                const unsigned* __restrict__ m3,
                                                float* __restrict__ s3, int NC) {
    int c = blockIdx.x * 256 + threadIdx.x;
    if (c >= NC) return;
    int hc = hclass[c];
    float ex = expf(zc[c] - fdec(m3[hc]));
    zc[c] = ex;
    atomicAdd(&s3[hc], ex);
}

__global__ __launch_bounds__(256) void k_class3(
    const int* __restrict__ hclass, const float* __restrict__ zc,
    const float* __restrict__ s3, const float* __restrict__ xclass,
    float* __restrict__ xeh, int NC) {
    int lane = threadIdx.x & 63;
    int c = blockIdx.x * 4 + (threadIdx.x >> 6);
    if (c >= NC) return;
    int hc = hclass[c];
    float gama = zc[c] / (s3[hc] + 1e-16f);
    float v0 = xclass[(size_t)c * 128 + lane], v1 = xclass[(size_t)c * 128 + 64 + lane];
    atomicAdd(&xeh[(size_t)hc * 128 + lane], gama * v0);
    atomicAdd(&xeh[(size_t)hc * 128 + 64 + lane], gama * v1);
}

extern "C" void kernel_launch(void* const* d_in, const int* in_sizes, int n_in,
                              void* d_out, int out_size, void* d_ws, size_t ws_size,
                              hipStream_t stream) {
    (void)n_in; (void)out_size; (void)ws_size;
    const float* xe   = (const float*)d_in[0];
    const int*   eidx = (const int*)d_in[1];
    const int*   rel  = (const int*)d_in[2];
    const float* remb = (const float*)d_in[4];
    const int*   cidx = (const int*)d_in[5];
    const int*   hcls = (const int*)d_in[6];
    const float* ah2  = (const float*)d_in[8];
    const float* ah3  = (const float*)d_in[9];
    const float* ah4  = (const float*)d_in[10];
    const float* at2  = (const float*)d_in[12];
    const float* at3  = (const float*)d_in[13];
    const float* ar2  = (const float*)d_in[15];
    const float* ac   = (const float*)d_in[16];
    const float* wh   = (const float*)d_in[17];
    const float* wt   = (const float*)d_in[18];
    const float* hww  = (const float*)d_in[19];
    const float* hwb  = (const float*)d_in[20];
    float* out = (float*)d_out;

    const int NE = in_sizes[0] / 256;
    const int E  = in_sizes[2];
    const int NR = in_sizes[4] / 128;
    const int NC = in_sizes[6];
    const int* hidx = eidx;
    const int* tidx = eidx + E;

    char* base = (char*)d_ws;
    size_t off0 = 0;
    auto alloc = [&](size_t bytes) -> char* {
        char* r = base + off0;
        off0 = (off0 + bytes + 255) & ~(size_t)255;
        return r;
    };
    float* hb   = (float*)alloc((size_t)NE * 4);
    float* eh4b = (float*)alloc((size_t)NE * 4);
    float2* pta = (float2*)alloc((size_t)NE * 8);
    float* er2b = (float*)alloc((size_t)NR * 4);
    float2* e2gs = (float2*)alloc((size_t)E * 8);
    float* zc   = (float*)alloc((size_t)NC * 4);
    unsigned short* wtb_hi = (unsigned short*)alloc((size_t)256 * 256 * 2);
    unsigned short* hwt_hi = (unsigned short*)alloc((size_t)128 * 128 * 2);
    unsigned short* xrh_hi = (unsigned short*)alloc((size_t)NE * 128 * 2);
    unsigned short* xrtn   = (unsigned short*)alloc((size_t)NE * 128 * 2);
    int* offb = (int*)alloc((size_t)NC * 4);
    int* curb = (int*)alloc((size_t)NC * 4);
    float* xclass = (float*)alloc((size_t)NC * 128 * 4);
    size_t zoff = off0;  // everything below is zero-initialized per launch
    unsigned* m3 = (unsigned*)alloc((size_t)NE * 4);
    float* s3    = (float*)alloc((size_t)NE * 4);
    int* cntb    = (int*)alloc((size_t)NC * 4);
    float* xeh   = (float*)alloc((size_t)NE * 128 * 4);
    size_t zbytes = off0 - zoff;

    hipMemsetAsync(base + zoff, 0, zbytes, stream);

    k_convW<<<(256 * 256 + 128 * 128 + 255) / 256, 256, 0, stream>>>(
        wh, wt, hww, wtb_hi, hwt_hi);
    k_rel<<<(NR + 3) / 4, 256, 0, stream>>>(remb, ar2, er2b, NR);

    // projection GEMM: depth-1 reg-staged A (f32 direct), bf16 B only,
    // bf16 mirrors (xrt pre-normalized) + fused dots + packed pta records
    k_mm_proj<<<((NE + 127) / 128) * 2, 256, 0, stream>>>(
        xe, wtb_hi, xrh_hi, xrtn, NE,
        ah2, ah3, ah4, at2, at3, hb, eh4b, pta, tidx);

    // class-CSR histogram/scan
    k_hist<<<(E + 255) / 256, 256, 0, stream>>>(cidx, cntb, E);
    k_scan<<<1, 1024, 0, stream>>>(cntb, offb, curb, NC);

    // fused level-2 logit + scatter (level-1 softmax cancels vs F.normalize)
    k_edgescatter<<<(E + 255) / 256, 256, 0, stream>>>(
        cidx, curb, hidx, tidx, rel, pta, hb, er2b, e2gs, E);

    k_spmm2<<<(NC + 3) / 4, 256, 0, stream>>>(offb, cntb, e2gs,
                                              (const unsigned*)xrtn, xclass,
                                              ac, eh4b, hcls, zc, m3, NC);
    k_class2<<<(NC + 255) / 256, 256, 0, stream>>>(hcls, zc, m3, s3, NC);
    k_class3<<<(NC + 3) / 4, 256, 0, stream>>>(hcls, zc, s3, xclass, xeh, NC);

    k_mm_hw<<<(NE + 127) / 128, 256, 0, stream>>>(
        xrh_hi, hwt_hi, out, hwb, xeh, NE);
}